// Round 12
// baseline (133.993 us; speedup 1.0000x reference)
//
#include <hip/hip_runtime.h>
#include <math.h>

// ---------------------------------------------------------------------------
// EstimatorQNNHybrid, round 12: R11 + two latency micro-opts.
//  (1) fc1/fc2 weights prefetched into wave-0 REGISTERS at kernel start
//      (hidden under conv1/conv2; kills the end-of-block dependent global
//      load tail). +20 VGPR on wave 0, cap 85 at 6 blocks/CU -> no spill.
//  (2) post-MFMA barrier dropped: h2p writes hit region 0 (dead xs), last
//      read two barriers earlier -> safe; 4 -> 3 barriers per block.
//  k_cnn : conv1 fp32 -> h1 packed fp16 [y][x][4 words]; conv2 = 9 MFMA/wave
//          (waves 0-2), A-frags single b128 gather; pool+fc in wave 0.
//  k_tail: BN1 + M build + quantum + BN2 (32 blocks, 2 spin grid-syncs).
// LDS: h2p/xs @0 (9216, aliased) | h1 @9216 (4480) | Bt @13696 (2304).
// ---------------------------------------------------------------------------

#define XS_S 34      // 29x34 padded fp32 input (row0/col0 pad), inside h2p
#define H1I_OFF 9216
#define BT_OFF  13696
#define SMEM_SZ 16000

typedef _Float16 half8 __attribute__((ext_vector_type(8)));
typedef float v4f __attribute__((ext_vector_type(4)));

// pack two f32 -> two f16 (RNE), low half = a
__device__ __forceinline__ unsigned pkf16(float a, float b) {
    _Float16 ha = (_Float16)a, hb = (_Float16)b;
    unsigned short ua = __builtin_bit_cast(unsigned short, ha);
    unsigned short ub = __builtin_bit_cast(unsigned short, hb);
    return ((unsigned)ub << 16) | (unsigned)ua;
}

__device__ __forceinline__ float2 cmul(float2 a, float2 b) {
    return make_float2(a.x * b.x - a.y * b.y, a.x * b.y + a.y * b.x);
}
__device__ __forceinline__ float2 cadd(float2 a, float2 b) {
    return make_float2(a.x + b.x, a.y + b.y);
}

__device__ __forceinline__ void apply_1q(const float2* src, float2* dst, int t,
                                         float2 g00, float2 g01, float2 g10, float2 g11, int p)
{
    int j = t >> 4, i = t & 15;
    int jb = (j >> p) & 1;
    int k0 = j & ~(1 << p);
    int k1 = j | (1 << p);
    float2 a0 = src[k0 * 16 + i], a1 = src[k1 * 16 + i];
    float2 r = jb ? cadd(cmul(g10, a0), cmul(g11, a1))
                  : cadd(cmul(g00, a0), cmul(g01, a1));
    dst[j * 16 + i] = r;
}

__device__ __forceinline__ void apply_ctrl(const float2* src, float2* dst, int t,
                                           float2 g00, float2 g01, float2 g10, float2 g11,
                                           int pc, int pt)
{
    int j = t >> 4, i = t & 15;
    float2 r;
    if (((j >> pc) & 1) == 0) {
        r = src[j * 16 + i];
    } else {
        int jb = (j >> pt) & 1;
        int k0 = j & ~(1 << pt);
        int k1 = j | (1 << pt);
        float2 a0 = src[k0 * 16 + i], a1 = src[k1 * 16 + i];
        r = jb ? cadd(cmul(g10, a0), cmul(g11, a1))
               : cadd(cmul(g00, a0), cmul(g01, a1));
    }
    dst[j * 16 + i] = r;
}

// ========================= K1: fused CNN per sample =========================
__global__ __launch_bounds__(256, 6) void k_cnn(
    const float* __restrict__ x,
    const float* __restrict__ w1, const float* __restrict__ b1,
    const float* __restrict__ w2, const float* __restrict__ b2,
    const float* __restrict__ fw1, const float* __restrict__ fb1,
    const float* __restrict__ fw2, const float* __restrict__ fb2,
    float* __restrict__ out_pre, unsigned int* __restrict__ counters)
{
    __shared__ __align__(16) char smem[SMEM_SZ];
    __shared__ float w1t[72];
    __shared__ float b1t[8], b2t[16];
    __shared__ float pool_s[16];

    const int t = threadIdx.x;
    const int b = blockIdx.x;
    const float* xg = x + b * 784;
    float* xs = (float*)smem;                          // conv1 input (dies after conv1)
    char* h1c = smem + H1I_OFF;                        // [14 rows][20 cells][16 B]

    // ---- wave-0 register prefetch of fc weights (hidden under conv) ----
    float4 pw1a, pw1b, pw1c, pw1d;
    float pw20 = 0.f, pw21 = 0.f, pw22 = 0.f, pw23 = 0.f, pb1 = 0.f;
    if (t < 64) {
        const float4* f4 = (const float4*)(fw1 + t * 16);
        pw1a = f4[0]; pw1b = f4[1]; pw1c = f4[2]; pw1d = f4[3];
        pw20 = fw2[t];       pw21 = fw2[64 + t];
        pw22 = fw2[128 + t]; pw23 = fw2[192 + t];
        pb1 = fb1[t];
    }

    // ---- phase A: pads + interior + small weights (disjoint writes) ----
    if (b == 0 && t < 2) counters[t] = 0u;             // sync counters for k_tail
    if (t < 57) {
        if (t < 29) xs[t] = 0.f;
        else        xs[(t - 28) * XS_S] = 0.f;
    }
    if (t >= 128 && t < 155) {                         // h1 pads: row0 (14) + col0 (13)
        int i = t - 128;
        int cell = (i < 14) ? i : (i - 13) * 20;
        *(uint4*)(h1c + cell * 16) = make_uint4(0, 0, 0, 0);
    }
    if (t >= 64 && t < 136) {                          // w1 [c][k] -> [k][8c]
        int i = t - 64;
        w1t[(i % 9) * 8 + (i / 9)] = w1[i];
    }
    if (t < 196) {                                     // interior, 196 float4
        float4 v = ((const float4*)xg)[t];
        int p = t * 4;
        int yy = p / 28, xx = p % 28;
        int base = (yy + 1) * XS_S + xx + 1;
        xs[base] = v.x; xs[base + 1] = v.y; xs[base + 2] = v.z; xs[base + 3] = v.w;
    }
    if (t < 8)  b1t[t] = b1[t];
    if (t < 16) b2t[t] = b2[t];
    __syncthreads();

    // ---- conv1 (1->8)+relu+pool: 169 lanes -> one b128 store; wave3: Bt ----
    if (t < 169) {
        const int py = t / 13, px = t % 13;
        float patch[4][4];
        #pragma unroll
        for (int dr = 0; dr < 4; ++dr) {
            int base = (2 * py + dr) * XS_S + 2 * px;
            float2 a = *(const float2*)&xs[base];
            float2 c = *(const float2*)&xs[base + 2];
            patch[dr][0] = a.x; patch[dr][1] = a.y;
            patch[dr][2] = c.x; patch[dr][3] = c.y;
        }
        float acc[8][2][2];
        #pragma unroll
        for (int c = 0; c < 8; ++c)
            #pragma unroll
            for (int dy = 0; dy < 2; ++dy)
                #pragma unroll
                for (int dx = 0; dx < 2; ++dx) acc[c][dy][dx] = 0.f;
        #pragma unroll
        for (int k = 0; k < 9; ++k) {
            const int ky = k / 3, kx = k % 3;
            float4 wA = *(const float4*)&w1t[k * 8];
            float4 wB = *(const float4*)&w1t[k * 8 + 4];
            float w8[8] = {wA.x, wA.y, wA.z, wA.w, wB.x, wB.y, wB.z, wB.w};
            #pragma unroll
            for (int c = 0; c < 8; ++c)
                #pragma unroll
                for (int dy = 0; dy < 2; ++dy)
                    #pragma unroll
                    for (int dx = 0; dx < 2; ++dx)
                        acc[c][dy][dx] = fmaf(patch[dy + ky][dx + kx], w8[c], acc[c][dy][dx]);
        }
        float v8[8];
        #pragma unroll
        for (int c = 0; c < 8; ++c) {
            float m = fmaxf(fmaxf(acc[c][0][0], acc[c][0][1]),
                            fmaxf(acc[c][1][0], acc[c][1][1])) + b1t[c];
            v8[c] = fmaxf(m, 0.f);
        }
        const int cell = (py + 1) * 20 + (px + 1);
        *(uint4*)(h1c + cell * 16) =
            make_uint4(pkf16(v8[0], v8[1]), pkf16(v8[2], v8[3]),
                       pkf16(v8[4], v8[5]), pkf16(v8[6], v8[7]));
    } else if (t >= 192) {
        // wave 3: Bt[oc][kidx*8+ic] <- f16(w2[oc][ic][kidx]), row 144B
        unsigned short* bt = (unsigned short*)(smem + BT_OFF);
        for (int i = t - 192; i < 1152; i += 64) {
            int oc = i / 72, r = i % 72, ic = r / 9, kidx = r % 9;
            _Float16 h = (_Float16)w2[i];
            bt[oc * 72 + kidx * 8 + ic] = __builtin_bit_cast(unsigned short, h);
        }
    }
    __syncthreads();

    // ---- conv2 = 9 MFMA/wave (waves 0-2), A-frags = single b128 gather -----
    const int wv_id = t >> 6, lane = t & 63, quad = lane >> 4, n = lane & 15;
    float* h2p = (float*)smem;                         // [144 pos][16 oc], aliases xs
    if (wv_id < 3) {
        v4f acc0 = {0.f, 0.f, 0.f, 0.f}, acc1 = acc0, acc2 = acc0;
        const half8 hz = {0, 0, 0, 0, 0, 0, 0, 0};
        half8 bfr[3];
        int koff[3];
        #pragma unroll
        for (int kc = 0; kc < 3; ++kc) {
            const int kidx = kc * 4 + quad;
            bfr[kc] = (kidx < 9)
                ? *(const half8*)(smem + BT_OFF + n * 144 + kc * 64 + quad * 16)
                : hz;
            koff[kc] = (kidx < 9) ? ((kidx / 3) * 20 + (kidx % 3)) * 16 : 0;
        }
        #pragma unroll
        for (int g = 0; g < 3; ++g) {
            const int m = (wv_id * 3 + g) * 16 + n;           // pos 0..143
            const int y = m / 12, xx2 = m % 12;
            const int pbase = (y * 20 + xx2) * 16;
            v4f* accp = (g == 0) ? &acc0 : (g == 1) ? &acc1 : &acc2;
            #pragma unroll
            for (int kc = 0; kc < 3; ++kc) {
                const int kidx = kc * 4 + quad;
                half8 af;
                if (kidx < 9) {
                    uint4 pw = *(const uint4*)(h1c + pbase + koff[kc]);
                    af = __builtin_bit_cast(half8, pw);
                } else {
                    af = hz;
                }
                *accp = __builtin_amdgcn_mfma_f32_16x16x32_f16(af, bfr[kc], *accp, 0, 0, 0);
            }
        }
        // no barrier needed: region 0 (xs) last read 2 barriers ago
        const int posb = (wv_id * 3) * 16 + quad * 4;
        #pragma unroll
        for (int r = 0; r < 4; ++r) h2p[(posb + r) * 16 + n]      = acc0[r];
        #pragma unroll
        for (int r = 0; r < 4; ++r) h2p[(posb + 16 + r) * 16 + n] = acc1[r];
        #pragma unroll
        for (int r = 0; r < 4; ++r) h2p[(posb + 32 + r) * 16 + n] = acc2[r];
    }
    __syncthreads();

    // ---- maxpool(2x2) + bias + relu + avg 6x6 + fc1 + fc2 in wave 0 --------
    if (t < 64) {
        const int oc = t >> 2, q = t & 3;
        const float bias = b2t[oc];
        float s = 0.f;
        #pragma unroll
        for (int r = 0; r < 9; ++r) {
            int idx = q * 9 + r;
            int pr = idx / 6, pc = idx % 6;
            int p00 = (2 * pr * 12 + 2 * pc) * 16 + oc;
            float m = fmaxf(fmaxf(h2p[p00], h2p[p00 + 16]),
                            fmaxf(h2p[p00 + 192], h2p[p00 + 208]));
            s += fmaxf(m + bias, 0.f);
        }
        s += __shfl_xor(s, 1);
        s += __shfl_xor(s, 2);
        if (q == 0) pool_s[oc] = s * (1.f / 36.f);     // wave-0 only, no barrier

        float a1 = pb1;
        a1 = fmaf(pool_s[0],  pw1a.x, a1); a1 = fmaf(pool_s[1],  pw1a.y, a1);
        a1 = fmaf(pool_s[2],  pw1a.z, a1); a1 = fmaf(pool_s[3],  pw1a.w, a1);
        a1 = fmaf(pool_s[4],  pw1b.x, a1); a1 = fmaf(pool_s[5],  pw1b.y, a1);
        a1 = fmaf(pool_s[6],  pw1b.z, a1); a1 = fmaf(pool_s[7],  pw1b.w, a1);
        a1 = fmaf(pool_s[8],  pw1c.x, a1); a1 = fmaf(pool_s[9],  pw1c.y, a1);
        a1 = fmaf(pool_s[10], pw1c.z, a1); a1 = fmaf(pool_s[11], pw1c.w, a1);
        a1 = fmaf(pool_s[12], pw1d.x, a1); a1 = fmaf(pool_s[13], pw1d.y, a1);
        a1 = fmaf(pool_s[14], pw1d.z, a1); a1 = fmaf(pool_s[15], pw1d.w, a1);
        float f = fmaxf(a1, 0.f);
        float p0 = f * pw20;
        float p1 = f * pw21;
        float p2 = f * pw22;
        float p3 = f * pw23;
        #pragma unroll
        for (int off = 32; off > 0; off >>= 1) {
            p0 += __shfl_down(p0, off);
            p1 += __shfl_down(p1, off);
            p2 += __shfl_down(p2, off);
            p3 += __shfl_down(p3, off);
        }
        if (t == 0) {
            ((float4*)out_pre)[b] = make_float4(p0 + fb2[0], p1 + fb2[1],
                                                p2 + fb2[2], p3 + fb2[3]);
        }
    }
}

// ====== K2: BN1 (grid sync #1, M build overlapped) + quantum + BN2 =========
__global__ __launch_bounds__(256) void k_tail(
    float* __restrict__ out_pre,
    const float* __restrict__ ng, const float* __restrict__ nb,
    const float* __restrict__ theta,
    const float* __restrict__ u_re, const float* __restrict__ u_im,
    const float* __restrict__ qg, const float* __restrict__ qb,
    float* __restrict__ bins1, float* __restrict__ bins2,
    unsigned int* __restrict__ counters)
{
    __shared__ float red[256];
    __shared__ float ss1[8], ss2[8];
    __shared__ float2 A[256], B[256], Ms[256];
    const int t = threadIdx.x;
    const int sidx = blockIdx.x * 256 + t;

    float4 o4 = ((const float4*)out_pre)[sidx];
    A[t] = make_float2(u_re[t], u_im[t]);
    float th0 = theta[0], th1 = theta[1], th2 = theta[2], th3 = theta[3];

    float vals[8] = {o4.x, o4.y, o4.z, o4.w,
                     o4.x * o4.x, o4.y * o4.y, o4.z * o4.z, o4.w * o4.w};
    #pragma unroll
    for (int off = 32; off > 0; off >>= 1)
        #pragma unroll
        for (int k = 0; k < 8; ++k) vals[k] += __shfl_down(vals[k], off);
    if ((t & 63) == 0) {
        int wid = t >> 6;
        #pragma unroll
        for (int k = 0; k < 8; ++k) red[wid * 8 + k] = vals[k];
    }
    __syncthreads();
    if (t < 8) {
        float s = red[t] + red[8 + t] + red[16 + t] + red[24 + t];
        __hip_atomic_store(&bins1[blockIdx.x * 8 + t], s,
                           __ATOMIC_RELEASE, __HIP_MEMORY_SCOPE_AGENT);
    }
    __syncthreads();
    if (t == 0) { __threadfence(); atomicAdd(&counters[0], 1u); }

    __syncthreads();
    float c0 = cosf(0.5f * th0), s0 = sinf(0.5f * th0);
    apply_1q(A, B, t, make_float2(c0, 0), make_float2(0, -s0),
                      make_float2(0, -s0), make_float2(c0, 0), 3);   // RX wire0
    __syncthreads();
    float c1 = cosf(0.5f * th1), s1 = sinf(0.5f * th1);
    apply_1q(B, A, t, make_float2(c1, 0), make_float2(-s1, 0),
                      make_float2(s1, 0), make_float2(c1, 0), 2);    // RY wire1
    __syncthreads();
    float c2 = cosf(0.5f * th2), s2 = sinf(0.5f * th2);
    apply_1q(A, B, t, make_float2(c2, -s2), make_float2(0, 0),
                      make_float2(0, 0), make_float2(c2, s2), 1);    // RZ wire2
    __syncthreads();
    float c3 = cosf(0.5f * th3), s3 = sinf(0.5f * th3);
    apply_ctrl(B, A, t, make_float2(c3, 0), make_float2(0, -s3),
                        make_float2(0, -s3), make_float2(c3, 0), 3, 0); // CRX w0->w3
    __syncthreads();
    const float hh = 0.70710678118654752440f;
    apply_1q(A, B, t, make_float2(hh, 0), make_float2(hh, 0),
                      make_float2(hh, 0), make_float2(-hh, 0), 0);   // H wire3
    __syncthreads();
    apply_1q(B, A, t, make_float2(0.5f, 0.5f), make_float2(0.5f, -0.5f),
                      make_float2(0.5f, -0.5f), make_float2(0.5f, 0.5f), 1); // SX wire2
    __syncthreads();
    apply_ctrl(A, B, t, make_float2(0, 0), make_float2(1, 0),
                        make_float2(1, 0), make_float2(0, 0), 0, 3); // CX w3->w0
    __syncthreads();
    Ms[t] = B[t];

    if (t == 0) {
        while (__hip_atomic_load(&counters[0], __ATOMIC_ACQUIRE,
                                 __HIP_MEMORY_SCOPE_AGENT) < 32u)
            __builtin_amdgcn_s_sleep(4);
    }
    __syncthreads();
    red[t] = bins1[t];
    __syncthreads();
    if (t < 8) {
        float s = 0.f;
        for (int bb = 0; bb < 32; ++bb) s += red[bb * 8 + t];
        red[t] = s;
    }
    if (t < 4) {
        float mean = red[t] * (1.f / 8192.f);
        float var = red[4 + t] * (1.f / 8192.f) - mean * mean;
        float sc = ng[t] * rsqrtf(var + 1e-5f);
        ss1[t] = sc;
        ss1[4 + t] = nb[t] - mean * sc;
    }
    __syncthreads();

    float a[4];
    a[0] = fmaf(ss1[0], o4.x, ss1[4]);
    a[1] = fmaf(ss1[1], o4.y, ss1[5]);
    a[2] = fmaf(ss1[2], o4.z, ss1[6]);
    a[3] = fmaf(ss1[3], o4.w, ss1[7]);
    float2 v[4][2];
    #pragma unroll
    for (int w = 0; w < 4; ++w) {
        float s, c;
        __sincosf(0.5f * a[w], &s, &c);
        float2 v0 = make_float2(c * c, -c * s);
        float2 v1 = make_float2(s * c, s * s);
        float2 n0 = make_float2(c * v0.x + s * v1.y, c * v0.y - s * v1.x);
        float2 n1 = make_float2(s * v0.y + c * v1.x, -s * v0.x + c * v1.y);
        v[w][0] = make_float2(c * n0.x - s * n1.x, c * n0.y - s * n1.y);
        v[w][1] = make_float2(s * n0.x + c * n1.x, s * n0.y + c * n1.y);
    }
    float2 st[16];
    #pragma unroll
    for (int idx = 0; idx < 16; ++idx) {
        float2 p = cmul(v[0][(idx >> 3) & 1], v[1][(idx >> 2) & 1]);
        p = cmul(p, v[2][(idx >> 1) & 1]);
        st[idx] = cmul(p, v[3][idx & 1]);
    }
    float q[4] = {0.f, 0.f, 0.f, 0.f};
    #pragma unroll
    for (int j = 0; j < 16; ++j) {
        float2 acc = make_float2(0.f, 0.f);
        #pragma unroll
        for (int i = 0; i < 16; ++i) {
            float2 mm = Ms[j * 16 + i];
            acc.x = fmaf(mm.x, st[i].x, acc.x);
            acc.x = fmaf(-mm.y, st[i].y, acc.x);
            acc.y = fmaf(mm.x, st[i].y, acc.y);
            acc.y = fmaf(mm.y, st[i].x, acc.y);
        }
        float pr = acc.x * acc.x + acc.y * acc.y;
        q[0] += ((j >> 3) & 1) ? -pr : pr;
        q[1] += ((j >> 2) & 1) ? -pr : pr;
        q[2] += ((j >> 1) & 1) ? -pr : pr;
        q[3] += (j & 1) ? -pr : pr;
    }

    float vals2[8] = {q[0], q[1], q[2], q[3],
                      q[0] * q[0], q[1] * q[1], q[2] * q[2], q[3] * q[3]};
    #pragma unroll
    for (int off = 32; off > 0; off >>= 1)
        #pragma unroll
        for (int k = 0; k < 8; ++k) vals2[k] += __shfl_down(vals2[k], off);
    __syncthreads();
    if ((t & 63) == 0) {
        int wid = t >> 6;
        #pragma unroll
        for (int k = 0; k < 8; ++k) red[wid * 8 + k] = vals2[k];
    }
    __syncthreads();
    if (t < 8) {
        float s = red[t] + red[8 + t] + red[16 + t] + red[24 + t];
        __hip_atomic_store(&bins2[blockIdx.x * 8 + t], s,
                           __ATOMIC_RELEASE, __HIP_MEMORY_SCOPE_AGENT);
    }
    __syncthreads();
    if (t == 0) {
        __threadfence();
        atomicAdd(&counters[1], 1u);
        while (__hip_atomic_load(&counters[1], __ATOMIC_ACQUIRE,
                                 __HIP_MEMORY_SCOPE_AGENT) < 32u)
            __builtin_amdgcn_s_sleep(4);
    }
    __syncthreads();
    red[t] = bins2[t];
    __syncthreads();
    if (t < 8) {
        float s = 0.f;
        for (int bb = 0; bb < 32; ++bb) s += red[bb * 8 + t];
        red[t] = s;
    }
    if (t < 4) {
        float m2 = red[t] * (1.f / 8192.f);
        float v2 = red[4 + t] * (1.f / 8192.f) - m2 * m2;
        float sc = qg[t] * rsqrtf(v2 + 1e-5f);
        ss2[t] = sc;
        ss2[4 + t] = qb[t] - m2 * sc;
    }
    __syncthreads();

    float4 r;
    r.x = a[0] + fmaf(ss2[0], q[0], ss2[4]);
    r.y = a[1] + fmaf(ss2[1], q[1], ss2[5]);
    r.z = a[2] + fmaf(ss2[2], q[2], ss2[6]);
    r.w = a[3] + fmaf(ss2[3], q[3], ss2[7]);
    ((float4*)out_pre)[sidx] = r;
}

// ===========================================================================
extern "C" void kernel_launch(void* const* d_in, const int* in_sizes, int n_in,
                              void* d_out, int out_size, void* d_ws, size_t ws_size,
                              hipStream_t stream)
{
    const float* x     = (const float*)d_in[0];
    const float* w1    = (const float*)d_in[1];
    const float* b1    = (const float*)d_in[2];
    const float* w2    = (const float*)d_in[3];
    const float* b2    = (const float*)d_in[4];
    const float* fw1   = (const float*)d_in[5];
    const float* fb1   = (const float*)d_in[6];
    const float* fw2   = (const float*)d_in[7];
    const float* fb2   = (const float*)d_in[8];
    const float* ng    = (const float*)d_in[9];
    const float* nb    = (const float*)d_in[10];
    const float* theta = (const float*)d_in[11];
    const float* ure   = (const float*)d_in[12];
    const float* uim   = (const float*)d_in[13];
    const float* qg    = (const float*)d_in[14];
    const float* qb    = (const float*)d_in[15];

    float* ws = (float*)d_ws;
    unsigned int* counters = (unsigned int*)d_ws;   // [2]
    float* bins1 = ws + 16;                         // 256 floats
    float* bins2 = ws + 16 + 256;                   // 256 floats
    float* out_pre = (float*)d_out;

    k_cnn<<<8192, 256, 0, stream>>>(x, w1, b1, w2, b2, fw1, fb1, fw2, fb2,
                                    out_pre, counters);
    k_tail<<<32, 256, 0, stream>>>(out_pre, ng, nb, theta, ure, uim, qg, qb,
                                   bins1, bins2, counters);
}

// Round 13
// 129.550 us; speedup vs baseline: 1.0343x; 1.0343x over previous
//
#include <hip/hip_runtime.h>
#include <math.h>

// ---------------------------------------------------------------------------
// EstimatorQNNHybrid, round 13: R11 structure + occupancy raise.
//  - k_cnn __launch_bounds__(256,8): VGPR cap 64 (R11 used 40 -> no spill),
//    LDS 16000x8=128KB <= 160KB -> 8 blocks/CU, 32/32 wave slots (was 24).
//    Latency-bound kernel -> +33% co-resident waves for tail/barrier hiding.
//  - R12's fc register prefetch reverted (neutral-negative, +20 VGPR).
//  - R12's barrier elimination kept (conv2 C-stores follow MFMA directly;
//    region 0 (xs) last read 2 barriers earlier; pool still barrier-guarded).
//  k_cnn : conv1 fp32 -> h1 packed fp16 [y][x][4 words]; conv2 = 9 MFMA/wave
//          (waves 0-2), A-frags single b128 gather; pool+fc in wave 0.
//  k_tail: BN1 + M build + quantum + BN2 (32 blocks, 2 spin grid-syncs).
// LDS: h2p/xs @0 (9216, aliased) | h1 @9216 (4480) | Bt @13696 (2304).
// ---------------------------------------------------------------------------

#define XS_S 34      // 29x34 padded fp32 input (row0/col0 pad), inside h2p
#define H1I_OFF 9216
#define BT_OFF  13696
#define SMEM_SZ 16000

typedef _Float16 half8 __attribute__((ext_vector_type(8)));
typedef float v4f __attribute__((ext_vector_type(4)));

// pack two f32 -> two f16 (RNE), low half = a
__device__ __forceinline__ unsigned pkf16(float a, float b) {
    _Float16 ha = (_Float16)a, hb = (_Float16)b;
    unsigned short ua = __builtin_bit_cast(unsigned short, ha);
    unsigned short ub = __builtin_bit_cast(unsigned short, hb);
    return ((unsigned)ub << 16) | (unsigned)ua;
}

__device__ __forceinline__ float2 cmul(float2 a, float2 b) {
    return make_float2(a.x * b.x - a.y * b.y, a.x * b.y + a.y * b.x);
}
__device__ __forceinline__ float2 cadd(float2 a, float2 b) {
    return make_float2(a.x + b.x, a.y + b.y);
}

__device__ __forceinline__ void apply_1q(const float2* src, float2* dst, int t,
                                         float2 g00, float2 g01, float2 g10, float2 g11, int p)
{
    int j = t >> 4, i = t & 15;
    int jb = (j >> p) & 1;
    int k0 = j & ~(1 << p);
    int k1 = j | (1 << p);
    float2 a0 = src[k0 * 16 + i], a1 = src[k1 * 16 + i];
    float2 r = jb ? cadd(cmul(g10, a0), cmul(g11, a1))
                  : cadd(cmul(g00, a0), cmul(g01, a1));
    dst[j * 16 + i] = r;
}

__device__ __forceinline__ void apply_ctrl(const float2* src, float2* dst, int t,
                                           float2 g00, float2 g01, float2 g10, float2 g11,
                                           int pc, int pt)
{
    int j = t >> 4, i = t & 15;
    float2 r;
    if (((j >> pc) & 1) == 0) {
        r = src[j * 16 + i];
    } else {
        int jb = (j >> pt) & 1;
        int k0 = j & ~(1 << pt);
        int k1 = j | (1 << pt);
        float2 a0 = src[k0 * 16 + i], a1 = src[k1 * 16 + i];
        r = jb ? cadd(cmul(g10, a0), cmul(g11, a1))
               : cadd(cmul(g00, a0), cmul(g01, a1));
    }
    dst[j * 16 + i] = r;
}

// ========================= K1: fused CNN per sample =========================
__global__ __launch_bounds__(256, 8) void k_cnn(
    const float* __restrict__ x,
    const float* __restrict__ w1, const float* __restrict__ b1,
    const float* __restrict__ w2, const float* __restrict__ b2,
    const float* __restrict__ fw1, const float* __restrict__ fb1,
    const float* __restrict__ fw2, const float* __restrict__ fb2,
    float* __restrict__ out_pre, unsigned int* __restrict__ counters)
{
    __shared__ __align__(16) char smem[SMEM_SZ];
    __shared__ float w1t[72];
    __shared__ float b1t[8], b2t[16];
    __shared__ float pool_s[16];

    const int t = threadIdx.x;
    const int b = blockIdx.x;
    const float* xg = x + b * 784;
    float* xs = (float*)smem;                          // conv1 input (dies after conv1)
    char* h1c = smem + H1I_OFF;                        // [14 rows][20 cells][16 B]

    // ---- phase A: pads + interior + small weights (disjoint writes) ----
    if (b == 0 && t < 2) counters[t] = 0u;             // sync counters for k_tail
    if (t < 57) {
        if (t < 29) xs[t] = 0.f;
        else        xs[(t - 28) * XS_S] = 0.f;
    }
    if (t >= 128 && t < 155) {                         // h1 pads: row0 (14) + col0 (13)
        int i = t - 128;
        int cell = (i < 14) ? i : (i - 13) * 20;
        *(uint4*)(h1c + cell * 16) = make_uint4(0, 0, 0, 0);
    }
    if (t >= 64 && t < 136) {                          // w1 [c][k] -> [k][8c]
        int i = t - 64;
        w1t[(i % 9) * 8 + (i / 9)] = w1[i];
    }
    if (t < 196) {                                     // interior, 196 float4
        float4 v = ((const float4*)xg)[t];
        int p = t * 4;
        int yy = p / 28, xx = p % 28;
        int base = (yy + 1) * XS_S + xx + 1;
        xs[base] = v.x; xs[base + 1] = v.y; xs[base + 2] = v.z; xs[base + 3] = v.w;
    }
    if (t < 8)  b1t[t] = b1[t];
    if (t < 16) b2t[t] = b2[t];
    __syncthreads();

    // ---- conv1 (1->8)+relu+pool: 169 lanes -> one b128 store; wave3: Bt ----
    if (t < 169) {
        const int py = t / 13, px = t % 13;
        float patch[4][4];
        #pragma unroll
        for (int dr = 0; dr < 4; ++dr) {
            int base = (2 * py + dr) * XS_S + 2 * px;
            float2 a = *(const float2*)&xs[base];
            float2 c = *(const float2*)&xs[base + 2];
            patch[dr][0] = a.x; patch[dr][1] = a.y;
            patch[dr][2] = c.x; patch[dr][3] = c.y;
        }
        float acc[8][2][2];
        #pragma unroll
        for (int c = 0; c < 8; ++c)
            #pragma unroll
            for (int dy = 0; dy < 2; ++dy)
                #pragma unroll
                for (int dx = 0; dx < 2; ++dx) acc[c][dy][dx] = 0.f;
        #pragma unroll
        for (int k = 0; k < 9; ++k) {
            const int ky = k / 3, kx = k % 3;
            float4 wA = *(const float4*)&w1t[k * 8];
            float4 wB = *(const float4*)&w1t[k * 8 + 4];
            float w8[8] = {wA.x, wA.y, wA.z, wA.w, wB.x, wB.y, wB.z, wB.w};
            #pragma unroll
            for (int c = 0; c < 8; ++c)
                #pragma unroll
                for (int dy = 0; dy < 2; ++dy)
                    #pragma unroll
                    for (int dx = 0; dx < 2; ++dx)
                        acc[c][dy][dx] = fmaf(patch[dy + ky][dx + kx], w8[c], acc[c][dy][dx]);
        }
        float v8[8];
        #pragma unroll
        for (int c = 0; c < 8; ++c) {
            float m = fmaxf(fmaxf(acc[c][0][0], acc[c][0][1]),
                            fmaxf(acc[c][1][0], acc[c][1][1])) + b1t[c];
            v8[c] = fmaxf(m, 0.f);
        }
        const int cell = (py + 1) * 20 + (px + 1);
        *(uint4*)(h1c + cell * 16) =
            make_uint4(pkf16(v8[0], v8[1]), pkf16(v8[2], v8[3]),
                       pkf16(v8[4], v8[5]), pkf16(v8[6], v8[7]));
    } else if (t >= 192) {
        // wave 3: Bt[oc][kidx*8+ic] <- f16(w2[oc][ic][kidx]), row 144B
        unsigned short* bt = (unsigned short*)(smem + BT_OFF);
        for (int i = t - 192; i < 1152; i += 64) {
            int oc = i / 72, r = i % 72, ic = r / 9, kidx = r % 9;
            _Float16 h = (_Float16)w2[i];
            bt[oc * 72 + kidx * 8 + ic] = __builtin_bit_cast(unsigned short, h);
        }
    }
    __syncthreads();

    // ---- conv2 = 9 MFMA/wave (waves 0-2), A-frags = single b128 gather -----
    const int wv_id = t >> 6, lane = t & 63, quad = lane >> 4, n = lane & 15;
    float* h2p = (float*)smem;                         // [144 pos][16 oc], aliases xs
    if (wv_id < 3) {
        v4f acc0 = {0.f, 0.f, 0.f, 0.f}, acc1 = acc0, acc2 = acc0;
        const half8 hz = {0, 0, 0, 0, 0, 0, 0, 0};
        half8 bfr[3];
        int koff[3];
        #pragma unroll
        for (int kc = 0; kc < 3; ++kc) {
            const int kidx = kc * 4 + quad;
            bfr[kc] = (kidx < 9)
                ? *(const half8*)(smem + BT_OFF + n * 144 + kc * 64 + quad * 16)
                : hz;
            koff[kc] = (kidx < 9) ? ((kidx / 3) * 20 + (kidx % 3)) * 16 : 0;
        }
        #pragma unroll
        for (int g = 0; g < 3; ++g) {
            const int m = (wv_id * 3 + g) * 16 + n;           // pos 0..143
            const int y = m / 12, xx2 = m % 12;
            const int pbase = (y * 20 + xx2) * 16;
            v4f* accp = (g == 0) ? &acc0 : (g == 1) ? &acc1 : &acc2;
            #pragma unroll
            for (int kc = 0; kc < 3; ++kc) {
                const int kidx = kc * 4 + quad;
                half8 af;
                if (kidx < 9) {
                    uint4 pw = *(const uint4*)(h1c + pbase + koff[kc]);
                    af = __builtin_bit_cast(half8, pw);
                } else {
                    af = hz;
                }
                *accp = __builtin_amdgcn_mfma_f32_16x16x32_f16(af, bfr[kc], *accp, 0, 0, 0);
            }
        }
        // no barrier needed before stores: region 0 (xs) last read 2 barriers ago
        const int posb = (wv_id * 3) * 16 + quad * 4;
        #pragma unroll
        for (int r = 0; r < 4; ++r) h2p[(posb + r) * 16 + n]      = acc0[r];
        #pragma unroll
        for (int r = 0; r < 4; ++r) h2p[(posb + 16 + r) * 16 + n] = acc1[r];
        #pragma unroll
        for (int r = 0; r < 4; ++r) h2p[(posb + 32 + r) * 16 + n] = acc2[r];
    }
    __syncthreads();

    // ---- maxpool(2x2) + bias + relu + avg 6x6 + fc1 + fc2 in wave 0 --------
    if (t < 64) {
        const int oc = t >> 2, q = t & 3;
        const float bias = b2t[oc];
        float s = 0.f;
        #pragma unroll
        for (int r = 0; r < 9; ++r) {
            int idx = q * 9 + r;
            int pr = idx / 6, pc = idx % 6;
            int p00 = (2 * pr * 12 + 2 * pc) * 16 + oc;
            float m = fmaxf(fmaxf(h2p[p00], h2p[p00 + 16]),
                            fmaxf(h2p[p00 + 192], h2p[p00 + 208]));
            s += fmaxf(m + bias, 0.f);
        }
        s += __shfl_xor(s, 1);
        s += __shfl_xor(s, 2);
        if (q == 0) pool_s[oc] = s * (1.f / 36.f);     // wave-0 only, no barrier

        const float4* f4 = (const float4*)(fw1 + t * 16);
        float4 wa = f4[0], wb = f4[1], wc = f4[2], wd = f4[3];
        float a1 = fb1[t];
        a1 = fmaf(pool_s[0],  wa.x, a1); a1 = fmaf(pool_s[1],  wa.y, a1);
        a1 = fmaf(pool_s[2],  wa.z, a1); a1 = fmaf(pool_s[3],  wa.w, a1);
        a1 = fmaf(pool_s[4],  wb.x, a1); a1 = fmaf(pool_s[5],  wb.y, a1);
        a1 = fmaf(pool_s[6],  wb.z, a1); a1 = fmaf(pool_s[7],  wb.w, a1);
        a1 = fmaf(pool_s[8],  wc.x, a1); a1 = fmaf(pool_s[9],  wc.y, a1);
        a1 = fmaf(pool_s[10], wc.z, a1); a1 = fmaf(pool_s[11], wc.w, a1);
        a1 = fmaf(pool_s[12], wd.x, a1); a1 = fmaf(pool_s[13], wd.y, a1);
        a1 = fmaf(pool_s[14], wd.z, a1); a1 = fmaf(pool_s[15], wd.w, a1);
        float f = fmaxf(a1, 0.f);
        float p0 = f * fw2[t];
        float p1 = f * fw2[64 + t];
        float p2 = f * fw2[128 + t];
        float p3 = f * fw2[192 + t];
        #pragma unroll
        for (int off = 32; off > 0; off >>= 1) {
            p0 += __shfl_down(p0, off);
            p1 += __shfl_down(p1, off);
            p2 += __shfl_down(p2, off);
            p3 += __shfl_down(p3, off);
        }
        if (t == 0) {
            ((float4*)out_pre)[b] = make_float4(p0 + fb2[0], p1 + fb2[1],
                                                p2 + fb2[2], p3 + fb2[3]);
        }
    }
}

// ====== K2: BN1 (grid sync #1, M build overlapped) + quantum + BN2 =========
__global__ __launch_bounds__(256) void k_tail(
    float* __restrict__ out_pre,
    const float* __restrict__ ng, const float* __restrict__ nb,
    const float* __restrict__ theta,
    const float* __restrict__ u_re, const float* __restrict__ u_im,
    const float* __restrict__ qg, const float* __restrict__ qb,
    float* __restrict__ bins1, float* __restrict__ bins2,
    unsigned int* __restrict__ counters)
{
    __shared__ float red[256];
    __shared__ float ss1[8], ss2[8];
    __shared__ float2 A[256], B[256], Ms[256];
    const int t = threadIdx.x;
    const int sidx = blockIdx.x * 256 + t;

    float4 o4 = ((const float4*)out_pre)[sidx];
    A[t] = make_float2(u_re[t], u_im[t]);
    float th0 = theta[0], th1 = theta[1], th2 = theta[2], th3 = theta[3];

    float vals[8] = {o4.x, o4.y, o4.z, o4.w,
                     o4.x * o4.x, o4.y * o4.y, o4.z * o4.z, o4.w * o4.w};
    #pragma unroll
    for (int off = 32; off > 0; off >>= 1)
        #pragma unroll
        for (int k = 0; k < 8; ++k) vals[k] += __shfl_down(vals[k], off);
    if ((t & 63) == 0) {
        int wid = t >> 6;
        #pragma unroll
        for (int k = 0; k < 8; ++k) red[wid * 8 + k] = vals[k];
    }
    __syncthreads();
    if (t < 8) {
        float s = red[t] + red[8 + t] + red[16 + t] + red[24 + t];
        __hip_atomic_store(&bins1[blockIdx.x * 8 + t], s,
                           __ATOMIC_RELEASE, __HIP_MEMORY_SCOPE_AGENT);
    }
    __syncthreads();
    if (t == 0) { __threadfence(); atomicAdd(&counters[0], 1u); }

    __syncthreads();
    float c0 = cosf(0.5f * th0), s0 = sinf(0.5f * th0);
    apply_1q(A, B, t, make_float2(c0, 0), make_float2(0, -s0),
                      make_float2(0, -s0), make_float2(c0, 0), 3);   // RX wire0
    __syncthreads();
    float c1 = cosf(0.5f * th1), s1 = sinf(0.5f * th1);
    apply_1q(B, A, t, make_float2(c1, 0), make_float2(-s1, 0),
                      make_float2(s1, 0), make_float2(c1, 0), 2);    // RY wire1
    __syncthreads();
    float c2 = cosf(0.5f * th2), s2 = sinf(0.5f * th2);
    apply_1q(A, B, t, make_float2(c2, -s2), make_float2(0, 0),
                      make_float2(0, 0), make_float2(c2, s2), 1);    // RZ wire2
    __syncthreads();
    float c3 = cosf(0.5f * th3), s3 = sinf(0.5f * th3);
    apply_ctrl(B, A, t, make_float2(c3, 0), make_float2(0, -s3),
                        make_float2(0, -s3), make_float2(c3, 0), 3, 0); // CRX w0->w3
    __syncthreads();
    const float hh = 0.70710678118654752440f;
    apply_1q(A, B, t, make_float2(hh, 0), make_float2(hh, 0),
                      make_float2(hh, 0), make_float2(-hh, 0), 0);   // H wire3
    __syncthreads();
    apply_1q(B, A, t, make_float2(0.5f, 0.5f), make_float2(0.5f, -0.5f),
                      make_float2(0.5f, -0.5f), make_float2(0.5f, 0.5f), 1); // SX wire2
    __syncthreads();
    apply_ctrl(A, B, t, make_float2(0, 0), make_float2(1, 0),
                        make_float2(1, 0), make_float2(0, 0), 0, 3); // CX w3->w0
    __syncthreads();
    Ms[t] = B[t];

    if (t == 0) {
        while (__hip_atomic_load(&counters[0], __ATOMIC_ACQUIRE,
                                 __HIP_MEMORY_SCOPE_AGENT) < 32u)
            __builtin_amdgcn_s_sleep(4);
    }
    __syncthreads();
    red[t] = bins1[t];
    __syncthreads();
    if (t < 8) {
        float s = 0.f;
        for (int bb = 0; bb < 32; ++bb) s += red[bb * 8 + t];
        red[t] = s;
    }
    if (t < 4) {
        float mean = red[t] * (1.f / 8192.f);
        float var = red[4 + t] * (1.f / 8192.f) - mean * mean;
        float sc = ng[t] * rsqrtf(var + 1e-5f);
        ss1[t] = sc;
        ss1[4 + t] = nb[t] - mean * sc;
    }
    __syncthreads();

    float a[4];
    a[0] = fmaf(ss1[0], o4.x, ss1[4]);
    a[1] = fmaf(ss1[1], o4.y, ss1[5]);
    a[2] = fmaf(ss1[2], o4.z, ss1[6]);
    a[3] = fmaf(ss1[3], o4.w, ss1[7]);
    float2 v[4][2];
    #pragma unroll
    for (int w = 0; w < 4; ++w) {
        float s, c;
        __sincosf(0.5f * a[w], &s, &c);
        float2 v0 = make_float2(c * c, -c * s);
        float2 v1 = make_float2(s * c, s * s);
        float2 n0 = make_float2(c * v0.x + s * v1.y, c * v0.y - s * v1.x);
        float2 n1 = make_float2(s * v0.y + c * v1.x, -s * v0.x + c * v1.y);
        v[w][0] = make_float2(c * n0.x - s * n1.x, c * n0.y - s * n1.y);
        v[w][1] = make_float2(s * n0.x + c * n1.x, s * n0.y + c * n1.y);
    }
    float2 st[16];
    #pragma unroll
    for (int idx = 0; idx < 16; ++idx) {
        float2 p = cmul(v[0][(idx >> 3) & 1], v[1][(idx >> 2) & 1]);
        p = cmul(p, v[2][(idx >> 1) & 1]);
        st[idx] = cmul(p, v[3][idx & 1]);
    }
    float q[4] = {0.f, 0.f, 0.f, 0.f};
    #pragma unroll
    for (int j = 0; j < 16; ++j) {
        float2 acc = make_float2(0.f, 0.f);
        #pragma unroll
        for (int i = 0; i < 16; ++i) {
            float2 mm = Ms[j * 16 + i];
            acc.x = fmaf(mm.x, st[i].x, acc.x);
            acc.x = fmaf(-mm.y, st[i].y, acc.x);
            acc.y = fmaf(mm.x, st[i].y, acc.y);
            acc.y = fmaf(mm.y, st[i].x, acc.y);
        }
        float pr = acc.x * acc.x + acc.y * acc.y;
        q[0] += ((j >> 3) & 1) ? -pr : pr;
        q[1] += ((j >> 2) & 1) ? -pr : pr;
        q[2] += ((j >> 1) & 1) ? -pr : pr;
        q[3] += (j & 1) ? -pr : pr;
    }

    float vals2[8] = {q[0], q[1], q[2], q[3],
                      q[0] * q[0], q[1] * q[1], q[2] * q[2], q[3] * q[3]};
    #pragma unroll
    for (int off = 32; off > 0; off >>= 1)
        #pragma unroll
        for (int k = 0; k < 8; ++k) vals2[k] += __shfl_down(vals2[k], off);
    __syncthreads();
    if ((t & 63) == 0) {
        int wid = t >> 6;
        #pragma unroll
        for (int k = 0; k < 8; ++k) red[wid * 8 + k] = vals2[k];
    }
    __syncthreads();
    if (t < 8) {
        float s = red[t] + red[8 + t] + red[16 + t] + red[24 + t];
        __hip_atomic_store(&bins2[blockIdx.x * 8 + t], s,
                           __ATOMIC_RELEASE, __HIP_MEMORY_SCOPE_AGENT);
    }
    __syncthreads();
    if (t == 0) {
        __threadfence();
        atomicAdd(&counters[1], 1u);
        while (__hip_atomic_load(&counters[1], __ATOMIC_ACQUIRE,
                                 __HIP_MEMORY_SCOPE_AGENT) < 32u)
            __builtin_amdgcn_s_sleep(4);
    }
    __syncthreads();
    red[t] = bins2[t];
    __syncthreads();
    if (t < 8) {
        float s = 0.f;
        for (int bb = 0; bb < 32; ++bb) s += red[bb * 8 + t];
        red[t] = s;
    }
    if (t < 4) {
        float m2 = red[t] * (1.f / 8192.f);
        float v2 = red[4 + t] * (1.f / 8192.f) - m2 * m2;
        float sc = qg[t] * rsqrtf(v2 + 1e-5f);
        ss2[t] = sc;
        ss2[4 + t] = qb[t] - m2 * sc;
    }
    __syncthreads();

    float4 r;
    r.x = a[0] + fmaf(ss2[0], q[0], ss2[4]);
    r.y = a[1] + fmaf(ss2[1], q[1], ss2[5]);
    r.z = a[2] + fmaf(ss2[2], q[2], ss2[6]);
    r.w = a[3] + fmaf(ss2[3], q[3], ss2[7]);
    ((float4*)out_pre)[sidx] = r;
}

// ===========================================================================
extern "C" void kernel_launch(void* const* d_in, const int* in_sizes, int n_in,
                              void* d_out, int out_size, void* d_ws, size_t ws_size,
                              hipStream_t stream)
{
    const float* x     = (const float*)d_in[0];
    const float* w1    = (const float*)d_in[1];
    const float* b1    = (const float*)d_in[2];
    const float* w2    = (const float*)d_in[3];
    const float* b2    = (const float*)d_in[4];
    const float* fw1   = (const float*)d_in[5];
    const float* fb1   = (const float*)d_in[6];
    const float* fw2   = (const float*)d_in[7];
    const float* fb2   = (const float*)d_in[8];
    const float* ng    = (const float*)d_in[9];
    const float* nb    = (const float*)d_in[10];
    const float* theta = (const float*)d_in[11];
    const float* ure   = (const float*)d_in[12];
    const float* uim   = (const float*)d_in[13];
    const float* qg    = (const float*)d_in[14];
    const float* qb    = (const float*)d_in[15];

    float* ws = (float*)d_ws;
    unsigned int* counters = (unsigned int*)d_ws;   // [2]
    float* bins1 = ws + 16;                         // 256 floats
    float* bins2 = ws + 16 + 256;                   // 256 floats
    float* out_pre = (float*)d_out;

    k_cnn<<<8192, 256, 0, stream>>>(x, w1, b1, w2, b2, fw1, fb1, fw2, fb2,
                                    out_pre, counters);
    k_tail<<<32, 256, 0, stream>>>(out_pre, ng, nb, theta, ure, uim, qg, qb,
                                   bins1, bins2, counters);
}